// Round 13
// baseline (335.329 us; speedup 1.0000x reference)
//
#include <hip/hip_runtime.h>

#define S_LEN 2048
#define DMODEL 1024
#define NH 16
#define NKVH 4
#define DKH 64
#define KVD 256
#define SCALE_LOG2E 0.18033688f  // (1/sqrt(64)) * log2(e)

typedef __bf16 bf16;
typedef bf16  bf16x8 __attribute__((ext_vector_type(8)));
typedef bf16  bf16x4 __attribute__((ext_vector_type(4)));
typedef float f32x4  __attribute__((ext_vector_type(4)));
typedef bf16x8 bf16x8_a __attribute__((may_alias));
typedef bf16x4 bf16x4_a __attribute__((may_alias));
typedef float f32x4g __attribute__((ext_vector_type(4), may_alias));

#define VWAIT(N)                                             \
    do {                                                     \
        asm volatile("s_waitcnt vmcnt(" #N ")" ::: "memory");\
        __builtin_amdgcn_sched_barrier(0);                   \
    } while (0)

#define LGKM0_BARRIER()                                       \
    do {                                                      \
        asm volatile("s_waitcnt lgkmcnt(0)" ::: "memory");    \
        __builtin_amdgcn_sched_barrier(0);                    \
        __builtin_amdgcn_s_barrier();                         \
        __builtin_amdgcn_sched_barrier(0);                    \
    } while (0)

__device__ __forceinline__ void gll16(const bf16* g, bf16* l) {
    __builtin_amdgcn_global_load_lds(
        (const __attribute__((address_space(1))) void*)g,
        (__attribute__((address_space(3))) void*)l, 16, 0, 0);
}

// ---------------- fused fp32 -> bf16 casts ----------------
__global__ __launch_bounds__(256) void cast3_bf16(const float* __restrict__ a,
                                                  const float* __restrict__ b,
                                                  const float* __restrict__ c,
                                                  bf16* __restrict__ oa, bf16* __restrict__ ob,
                                                  bf16* __restrict__ oc, int n4) {
    const float* src = blockIdx.y == 0 ? a : blockIdx.y == 1 ? b : c;
    bf16* dst = blockIdx.y == 0 ? oa : blockIdx.y == 1 ? ob : oc;
    int stride = gridDim.x * blockDim.x;
    for (int i = blockIdx.x * blockDim.x + threadIdx.x; i < n4; i += stride) {
        f32x4g v = ((const f32x4g*)src)[i];
        bf16x4 o;
        o[0] = (bf16)v[0]; o[1] = (bf16)v[1]; o[2] = (bf16)v[2]; o[3] = (bf16)v[3];
        ((bf16x4*)dst)[i] = o;
    }
}

__global__ __launch_bounds__(256) void cast2_bf16(const float* __restrict__ a,
                                                  const float* __restrict__ b,
                                                  bf16* __restrict__ oa, bf16* __restrict__ ob,
                                                  int n4) {
    const float* src = blockIdx.y == 0 ? a : b;
    bf16* dst = blockIdx.y == 0 ? oa : ob;
    int stride = gridDim.x * blockDim.x;
    for (int i = blockIdx.x * blockDim.x + threadIdx.x; i < n4; i += stride) {
        f32x4g v = ((const f32x4g*)src)[i];
        bf16x4 o;
        o[0] = (bf16)v[0]; o[1] = (bf16)v[1]; o[2] = (bf16)v[2]; o[3] = (bf16)v[3];
        ((bf16x4*)dst)[i] = o;
    }
}

// ---------------- NT GEMM: C[m][n] = sum_k A[m][k]*Bw[n][k] + bias[n] ----------------
template <int OUTF32>
__global__ __launch_bounds__(256) void gemm_bt(const bf16* __restrict__ A,
                                               const bf16* __restrict__ Bw,
                                               const float* __restrict__ bias,
                                               void* __restrict__ Cout,
                                               int M, int N, int K) {
    __shared__ bf16 As[4096];  // 128 x 32
    __shared__ bf16 Bs[4096];
    const int bm = blockIdx.x, bn = blockIdx.y;
    const int tid = threadIdx.x, wave = tid >> 6, lane = tid & 63;
    const int l15 = lane & 15, lhi = lane >> 4;
    const int wr = (wave >> 1) * 64, wc = (wave & 1) * 64;
    f32x4 acc[4][4] = {};
    const size_t arow0 = (size_t)bm * 128 * K;
    const size_t brow0 = (size_t)bn * 128 * K;

    for (int kt = 0; kt < K; kt += 32) {
#pragma unroll
        for (int i = 0; i < 2; ++i) {
            int base = i * 2048 + wave * 512;
            int flat = base + lane * 8;
            int r = flat >> 5, c = flat & 31;
            gll16(A + arow0 + (size_t)r * K + kt + c, &As[base]);
            gll16(Bw + brow0 + (size_t)r * K + kt + c, &Bs[base]);
        }
        __syncthreads();
        bf16x8 af[4], bfr[4];
#pragma unroll
        for (int mi = 0; mi < 4; ++mi)
            af[mi] = *(const bf16x8_a*)&As[(wr + mi * 16 + l15) * 32 + lhi * 8];
#pragma unroll
        for (int ni = 0; ni < 4; ++ni)
            bfr[ni] = *(const bf16x8_a*)&Bs[(wc + ni * 16 + l15) * 32 + lhi * 8];
#pragma unroll
        for (int mi = 0; mi < 4; ++mi)
#pragma unroll
            for (int ni = 0; ni < 4; ++ni)
                acc[mi][ni] = __builtin_amdgcn_mfma_f32_16x16x32_bf16(
                    af[mi], bfr[ni], acc[mi][ni], 0, 0, 0);
        __syncthreads();
    }
#pragma unroll
    for (int mi = 0; mi < 4; ++mi)
#pragma unroll
        for (int ni = 0; ni < 4; ++ni)
#pragma unroll
            for (int j = 0; j < 4; ++j) {
                int row = bm * 128 + wr + mi * 16 + lhi * 4 + j;
                int col = bn * 128 + wc + ni * 16 + l15;
                float v = acc[mi][ni][j] + bias[col];
                if (OUTF32)
                    ((float*)Cout)[(size_t)row * N + col] = v;
                else
                    ((bf16*)Cout)[(size_t)row * N + col] = (bf16)v;
            }
}

// ---------------- V transpose: Vp[b*2048+s][g*64+d] -> VT[b][g][d][s] ----------------
__global__ __launch_bounds__(256) void vtrans(const bf16* __restrict__ V,
                                              bf16* __restrict__ VT) {
    __shared__ bf16 t[64][65];
    const int s0 = blockIdx.x * 64;
    const int bg = blockIdx.y;
    const int b = bg >> 2, g = bg & 3;
#pragma unroll
    for (int i = 0; i < 16; ++i) {
        int flat = threadIdx.x + i * 256;
        int r = flat >> 6, c = flat & 63;
        t[c][r] = V[(size_t)(b * S_LEN + s0 + r) * KVD + g * DKH + c];
    }
    __syncthreads();
#pragma unroll
    for (int i = 0; i < 16; ++i) {
        int flat = threadIdx.x + i * 256;
        int d = flat >> 6, si = flat & 63;
        VT[((size_t)bg * DKH + d) * S_LEN + s0 + si] = t[d][si];
    }
}

// ---------------- merged attention v4: producer/consumer wave specialization ----------------
// grid 2048 (XCD-swizzled) = bh(32) x qt(64: 32 q-rows); block 1024 = 16 waves.
// Pass A (all 16 waves): denominators, 16 chunks x 128 keys, K ring-2.
// Pass B: waves 0-7 compute (QK, exp, P->Pst ring-2, PV); waves 8-15 STORE ONLY
// (read Pst, widen, 1KB-contiguous f32 row stores, vmcnt NEVER waited -> deep pipelining).
__global__ __launch_bounds__(1024, 8) void attn_all(const bf16* __restrict__ Qp,
                                                    const bf16* __restrict__ Kp,
                                                    const bf16* __restrict__ VT,
                                                    float* __restrict__ attn_out,
                                                    bf16* __restrict__ ctx) {
    __shared__ bf16 KV[16384];   // 32 KB: passA = 2 x 16KB ring; passB = K{0,1}(0-16K), V{0,1}(16-32K)
    __shared__ bf16 Pst[16384];  // 32 KB: ring-2 of [32 q][256 k] bf16 (16 KB each); head = red scratch
    const int raw = blockIdx.x;
    const int wg = (raw & 7) * 256 + (raw >> 3);  // 2048 % 8 == 0: bijective
    const int bh = wg >> 6;
    const int qt = wg & 63;
    const int h = bh & (NH - 1), b = bh >> 4, g = h >> 2;
    const int tid = threadIdx.x, wave = tid >> 6, lane = tid & 63;
    const int l15 = lane & 15, lhi = lane >> 4;
    const int qrow0 = qt * 32;
    const int sw = (l15 & 7) << 4;
    char* kvb = (char*)&KV[0];
    char* pstb0 = (char*)&Pst[0];

    // ================= pass A: all 16 waves, 16 chunks x 128 keys =================
    {
        const int wq2 = wave >> 3, wk8 = wave & 7;
        const bf16* qbA =
            Qp + (size_t)(b * S_LEN + qrow0 + wq2 * 16 + l15) * DMODEL + h * DKH + lhi * 8;
        bf16x8 aqA0 = *(const bf16x8_a*)qbA;
        bf16x8 aqA1 = *(const bf16x8_a*)(qbA + 32);

        const int srowA = tid >> 3;  // 0..127
        const int sccA = (tid & 7) ^ (srowA & 7);
        const bf16* ksrcA = Kp + (size_t)(b * S_LEN + srowA) * KVD + g * DKH + sccA * 8;

        gll16(ksrcA, (bf16*)(kvb + wave * 1024));  // chunk 0 -> bufA0
        float lsum = 0.f;
        for (int c = 0; c < 16; ++c) {
            VWAIT(0);  // own K(c) slice landed
            __builtin_amdgcn_s_barrier();
            if (c < 15)
                gll16(ksrcA + (size_t)((c + 1) * 128) * KVD,
                      (bf16*)(kvb + ((c + 1) & 1) * 16384 + wave * 1024));
            const char* kc = kvb + (c & 1) * 16384;
            const int rb = (wk8 * 16 + l15) * 128;
            bf16x8 k0 = *(const bf16x8_a*)(kc + rb + ((lhi * 16) ^ sw));
            bf16x8 k1 = *(const bf16x8_a*)(kc + rb + ((lhi * 16 + 64) ^ sw));
            f32x4 a = {0.f, 0.f, 0.f, 0.f};
            __builtin_amdgcn_s_setprio(1);
            a = __builtin_amdgcn_mfma_f32_16x16x32_bf16(k0, aqA0, a, 0, 0, 0);
            a = __builtin_amdgcn_mfma_f32_16x16x32_bf16(k1, aqA1, a, 0, 0, 0);
            __builtin_amdgcn_s_setprio(0);
            lsum += __builtin_exp2f(a[0] * SCALE_LOG2E) + __builtin_exp2f(a[1] * SCALE_LOG2E) +
                    __builtin_exp2f(a[2] * SCALE_LOG2E) + __builtin_exp2f(a[3] * SCALE_LOG2E);
        }
        lsum += __shfl_xor(lsum, 16, 64);
        lsum += __shfl_xor(lsum, 32, 64);
        float* red = (float*)pstb0;  // [16 waves][16 q]
        if (lane < 16) red[wave * 16 + lane] = lsum;
    }
    LGKM0_BARRIER();  // pass A reads done + red visible

    // pass-B prologue staging: compute threads (tid<512) stage K(0), V(0)
    const int srow = tid >> 3;  // valid for tid<512: 0..63
    const int scc = (tid & 7) ^ (srow & 7);
    const bf16* ksrc = Kp + (size_t)(b * S_LEN + srow) * KVD + g * DKH + scc * 8;
    const bf16* vsrc = VT + ((size_t)(b * NKVH + g) * DKH + srow) * S_LEN + scc * 8;
    if (tid < 512) {
        gll16(ksrc, (bf16*)(kvb + wave * 1024));          // K0 -> [0,8K)
        gll16(vsrc, (bf16*)(kvb + 16384 + wave * 1024));  // V0 -> [16K,24K)
    }
    float rinv = 0.f;
    if (wave < 8) {
        const float* red = (const float*)pstb0;
        const int wq = wave >> 2;
        float lt = 0.f;
#pragma unroll
        for (int j = 0; j < 8; ++j) lt += red[(wq * 8 + j) * 16 + l15];
        rinv = 1.0f / lt;
    }
    LGKM0_BARRIER();  // red reads drained -> Pst writable

    // ================= pass B =================
    if (wave < 8) {
        // -------- compute waves: QK -> P -> PV; loads only in vmcnt queue --------
        const int wq = wave >> 2, wk = wave & 3;
        const int ql = wq * 16 + l15;
        const bf16* qb =
            Qp + (size_t)(b * S_LEN + qrow0 + wq * 16 + l15) * DMODEL + h * DKH + lhi * 8;
        bf16x8 aq0 = *(const bf16x8_a*)qb;
        bf16x8 aq1 = *(const bf16x8_a*)(qb + 32);
        f32x4 cacc = {0.f, 0.f, 0.f, 0.f};
        const int qsw = (ql & 7) << 4;

        for (int c = 0; c < 32; ++c) {
            VWAIT(0);  // K(c), V(c), (+aq at c=0) retired
            __builtin_amdgcn_s_barrier();  // barrier #1: K/V published
            if (c < 31) {
                gll16(ksrc + (size_t)((c + 1) * 64) * KVD,
                      (bf16*)(kvb + ((c + 1) & 1) * 8192 + wave * 1024));
                gll16(vsrc + (c + 1) * 64,
                      (bf16*)(kvb + 16384 + ((c + 1) & 1) * 8192 + wave * 1024));
            }
            // QK(c): S[key = c*64 + wk*16 + lhi*4 + j][q = ql]
            const char* kc = kvb + (c & 1) * 8192;
            const int rb = (wk * 16 + l15) * 128;
            bf16x8 k0 = *(const bf16x8_a*)(kc + rb + ((lhi * 16) ^ sw));
            bf16x8 k1 = *(const bf16x8_a*)(kc + rb + ((lhi * 16 + 64) ^ sw));
            f32x4 a = {0.f, 0.f, 0.f, 0.f};
            __builtin_amdgcn_s_setprio(1);
            a = __builtin_amdgcn_mfma_f32_16x16x32_bf16(k0, aq0, a, 0, 0, 0);
            a = __builtin_amdgcn_mfma_f32_16x16x32_bf16(k1, aq1, a, 0, 0, 0);
            __builtin_amdgcn_s_setprio(0);
            // P(c) -> Pst[(c>>2)&1], column block c&3 (normalized, bf16, swizzled)
            char* pstb = pstb0 + ((c >> 2) & 1) * 16384;
            bf16x4 pb4;
#pragma unroll
            for (int j = 0; j < 4; ++j)
                pb4[j] = (bf16)(__builtin_exp2f(a[j] * SCALE_LOG2E) * rinv);
            *(bf16x4_a*)(pstb + ql * 512 +
                         (((c & 3) * 128 + wk * 32 + lhi * 8) ^ qsw)) = pb4;
            LGKM0_BARRIER();  // barrier #2: P(c) visible block-wide
            // PV(c)
            bf16x8 ap0 =
                *(const bf16x8_a*)(pstb + ql * 512 + (((c & 3) * 128 + lhi * 16) ^ qsw));
            bf16x8 ap1 = *(const bf16x8_a*)(pstb + ql * 512 +
                                            (((c & 3) * 128 + 64 + lhi * 16) ^ qsw));
            const char* vc = kvb + 16384 + (c & 1) * 8192;
            const int vb = (wk * 16 + l15) * 128;
            bf16x8 v0 = *(const bf16x8_a*)(vc + vb + ((lhi * 16) ^ sw));
            bf16x8 v1 = *(const bf16x8_a*)(vc + vb + ((lhi * 16 + 64) ^ sw));
            __builtin_amdgcn_s_setprio(1);
            cacc = __builtin_amdgcn_mfma_f32_16x16x32_bf16(ap0, v0, cacc, 0, 0, 0);
            cacc = __builtin_amdgcn_mfma_f32_16x16x32_bf16(ap1, v1, cacc, 0, 0, 0);
            __builtin_amdgcn_s_setprio(0);
        }
        // ctx write (P pre-normalized)
#pragma unroll
        for (int j = 0; j < 4; ++j) {
            int row = qrow0 + wq * 16 + lhi * 4 + j;
            ctx[(size_t)(b * S_LEN + row) * DMODEL + h * DKH + wk * 16 + l15] =
                (bf16)cacc[j];
        }
    } else {
        // -------- storer waves: Pst -> 1KB-contiguous f32 stores; vmcnt never waited --------
        const int sw2 = wave - 8;  // 0..7
        float* arow = attn_out + ((size_t)bh * S_LEN + qrow0) * S_LEN;
        for (int c = 0; c < 32; ++c) {
            __builtin_amdgcn_s_barrier();  // match compute barrier #1
            LGKM0_BARRIER();               // match compute barrier #2; P(c) visible
            if ((c & 3) == 3) {
                const int G = c >> 2;
                const char* pstb = pstb0 + (G & 1) * 16384;
#pragma unroll
                for (int r = 0; r < 4; ++r) {
                    int row = sw2 * 4 + r;
                    bf16x4 pv4 = *(const bf16x4_a*)(pstb + row * 512 +
                                                    ((lane * 8) ^ ((row & 7) << 4)));
                    f32x4 pf4;
#pragma unroll
                    for (int j = 0; j < 4; ++j) pf4[j] = (float)pv4[j];
                    *(f32x4g*)(arow + (size_t)row * S_LEN + G * 256 + lane * 4) = pf4;
                }
            }
        }
    }
}

extern "C" void kernel_launch(void* const* d_in, const int* in_sizes, int n_in,
                              void* d_out, int out_size, void* d_ws, size_t ws_size,
                              hipStream_t stream) {
    const float* query = (const float*)d_in[0];
    const float* key_i = (const float*)d_in[1];
    const float* value = (const float*)d_in[2];
    const float* Wq = (const float*)d_in[3];
    const float* bq = (const float*)d_in[4];
    const float* Wk = (const float*)d_in[5];
    const float* bk = (const float*)d_in[6];
    const float* Wv = (const float*)d_in[7];
    const float* bv = (const float*)d_in[8];
    const float* Wo = (const float*)d_in[9];
    const float* bo = (const float*)d_in[10];

    char* ws = (char*)d_ws;
    bf16* qx = (bf16*)(ws + 0);
    bf16* kx = (bf16*)(ws + ((size_t)8 << 20));
    bf16* vx = (bf16*)(ws + ((size_t)16 << 20));
    bf16* wqx = (bf16*)(ws + ((size_t)32 << 20));
    bf16* wkx = (bf16*)(ws + ((size_t)34 << 20));
    bf16* wvx = (bf16*)(ws + ((size_t)34 << 20) + ((size_t)512 << 10));
    bf16* wox = (bf16*)(ws + ((size_t)35 << 20));
    bf16* Qp = (bf16*)(ws + ((size_t)37 << 20));
    bf16* Kp = (bf16*)(ws + ((size_t)45 << 20));
    bf16* Vp = (bf16*)(ws + ((size_t)47 << 20));
    bf16* VT = (bf16*)(ws + ((size_t)49 << 20));
    bf16* ctxb = (bf16*)(ws + ((size_t)51 << 20));

    const int BS = 2 * S_LEN;  // 4096 rows

    cast3_bf16<<<dim3(1024, 3), 256, 0, stream>>>(query, key_i, value, qx, kx, vx,
                                                  BS * DMODEL / 4);
    cast2_bf16<<<dim3(1024, 2), 256, 0, stream>>>(Wq, Wo, wqx, wox, DMODEL * DMODEL / 4);
    cast2_bf16<<<dim3(256, 2), 256, 0, stream>>>(Wk, Wv, wkx, wvx, KVD * DMODEL / 4);

    gemm_bt<0><<<dim3(32, 8), 256, 0, stream>>>(qx, wqx, bq, Qp, BS, DMODEL, DMODEL);
    gemm_bt<0><<<dim3(32, 2), 256, 0, stream>>>(kx, wkx, bk, Kp, BS, KVD, DMODEL);
    gemm_bt<0><<<dim3(32, 2), 256, 0, stream>>>(vx, wvx, bv, Vp, BS, KVD, DMODEL);

    vtrans<<<dim3(32, 8), 256, 0, stream>>>(Vp, VT);

    float* attn_out = (float*)d_out + (size_t)BS * DMODEL;
    attn_all<<<2048, 1024, 0, stream>>>(Qp, Kp, VT, attn_out, ctxb);

    gemm_bt<1><<<dim3(32, 8), 256, 0, stream>>>(ctxb, wox, bo, (float*)d_out, BS, DMODEL, DMODEL);
}